// Round 1
// baseline (261.168 us; speedup 1.0000x reference)
//
#include <hip/hip_runtime.h>

#define OUT_H 7
#define OUT_W 7

// Geometry fixed by the problem's setup_inputs(): B=4, C=256, H=W=200, N=512.
// N and C are derived from sizes at launch for safety; H/W hardcoded.
#define FEAT_H 200
#define FEAT_W 200

__global__ __launch_bounds__(256) void roialign_kernel(
    const float* __restrict__ feat,   // (B, C, H, W)
    const int*   __restrict__ rois,   // (N, 5): b, x1, y1, x2, y2
    float*       __restrict__ out,    // (N, C, 7, 7)
    int N, int C, int total)
{
    int idx = blockIdx.x * blockDim.x + threadIdx.x;
    if (idx >= total) return;

    const int H = FEAT_H, W = FEAT_W;

    // Decompose flat output index (n, c, jy, jx) — jx fastest → coalesced store.
    int jx = idx % OUT_W;
    int t  = idx / OUT_W;
    int jy = t % OUT_H;
    t /= OUT_H;
    int c = t % C;
    int n = t / C;

    const int* r = rois + n * 5;
    int b = r[0];
    float x1 = (float)r[1];
    float y1 = (float)r[2];
    float x2 = (float)r[3];
    float y2 = (float)r[4];

    // Match reference order of operations: (jy * (y2-y1)) / 6
    float sy = y1 + ((float)jy * (y2 - y1)) / (float)(OUT_H - 1);
    float sx = x1 + ((float)jx * (x2 - x1)) / (float)(OUT_W - 1);

    float y0f = floorf(sy);
    float x0f = floorf(sx);
    float wy = sy - y0f;
    float wx = sx - x0f;

    int y0  = min(max((int)y0f, 0), H - 1);
    int y1i = min(y0 + 1, H - 1);
    int x0  = min(max((int)x0f, 0), W - 1);
    int x1i = min(x0 + 1, W - 1);

    const float* fp = feat + ((size_t)b * C + c) * (size_t)(H * W);
    float v00 = fp[y0  * W + x0 ];
    float v01 = fp[y0  * W + x1i];
    float v10 = fp[y1i * W + x0 ];
    float v11 = fp[y1i * W + x1i];

    float omwy = 1.0f - wy;
    float omwx = 1.0f - wx;
    out[idx] = v00 * omwy * omwx + v01 * omwy * wx
             + v10 * wy   * omwx + v11 * wy   * wx;
}

extern "C" void kernel_launch(void* const* d_in, const int* in_sizes, int n_in,
                              void* d_out, int out_size, void* d_ws, size_t ws_size,
                              hipStream_t stream)
{
    const float* feat = (const float*)d_in[0];
    const int*   rois = (const int*)d_in[1];
    float*       out  = (float*)d_out;

    int N = in_sizes[1] / 5;                       // 512
    int C = out_size / (N * OUT_H * OUT_W);        // 256
    int total = out_size;                          // N*C*49

    int threads = 256;
    int blocks = (total + threads - 1) / threads;
    roialign_kernel<<<blocks, threads, 0, stream>>>(feat, rois, out, N, C, total);
}